// Round 4
// baseline (324.749 us; speedup 1.0000x reference)
//
#include <hip/hip_runtime.h>
#include <math.h>

#define B_ 8
#define N_ 2048
#define D_ 512
#define NROWS (B_ * N_)   // 16384
#define HTS (NROWS + 32)  // padded Ht row stride (breaks 32KB L2 aliasing)
#define NEG_ALPHA 0.1f

typedef __bf16 bf16;
typedef __bf16 bf16x4 __attribute__((ext_vector_type(4)));
typedef __bf16 bf16x8 __attribute__((ext_vector_type(8)));
typedef float f32x4 __attribute__((ext_vector_type(4)));
typedef float f32x16 __attribute__((ext_vector_type(16)));

// ---------------------------------------------------------------------------
// k_prep_wa: Wt[dout][din] = bf16(W[din][dout]);  wa{1,2} = W @ a{1,2} (fp32)
// grid 512: every block transposes one dout row; blocks 0..127 also do wa.
// ---------------------------------------------------------------------------
__global__ __launch_bounds__(256) void k_prep_wa(const float* __restrict__ W,
                                                 const float* __restrict__ a1,
                                                 const float* __restrict__ a2,
                                                 bf16* __restrict__ Wt,
                                                 float* __restrict__ wa1,
                                                 float* __restrict__ wa2) {
  const int t = threadIdx.x;
  const int bid = blockIdx.x;
#pragma unroll
  for (int p = 0; p < 2; ++p) {
    int din = t + p * 256;
    Wt[bid * D_ + din] = (bf16)W[(size_t)din * D_ + bid];
  }
  if (bid < 128) {
    const int wv = t >> 6, lane = t & 63;
    const int row = bid * 4 + wv;
    const float* wr = W + (size_t)row * D_;
    float d1 = 0.f, d2 = 0.f;
#pragma unroll
    for (int p = 0; p < 8; ++p) {
      int c = lane + p * 64;
      float w = wr[c];
      d1 = fmaf(w, a1[c], d1);
      d2 = fmaf(w, a2[c], d2);
    }
#pragma unroll
    for (int off = 32; off > 0; off >>= 1) {
      d1 += __shfl_down(d1, off, 64);
      d2 += __shfl_down(d2, off, 64);
    }
    if (lane == 0) {
      wa1[row] = d1;
      wa2[row] = d2;
    }
  }
}

// ---------------------------------------------------------------------------
// k_scores_x: s1[r] = X[r,:].wa1 ; s2[r] = X[r,:].wa2 (fp32-exact logits)
// ---------------------------------------------------------------------------
__global__ __launch_bounds__(256) void k_scores_x(const float* __restrict__ X,
                                                  const float* __restrict__ wa1,
                                                  const float* __restrict__ wa2,
                                                  float* __restrict__ s1,
                                                  float* __restrict__ s2) {
  const int wv = threadIdx.x >> 6, lane = threadIdx.x & 63;
  const int r = blockIdx.x * 4 + wv;
  const float* x = X + (size_t)r * D_;
  float d1 = 0.f, d2 = 0.f;
#pragma unroll
  for (int p = 0; p < 2; ++p) {
    int c = lane * 4 + p * 256;
    float4 xv = *(const float4*)&x[c];
    float4 w1 = *(const float4*)&wa1[c];
    float4 w2 = *(const float4*)&wa2[c];
    d1 += xv.x * w1.x + xv.y * w1.y + xv.z * w1.z + xv.w * w1.w;
    d2 += xv.x * w2.x + xv.y * w2.y + xv.z * w2.z + xv.w * w2.w;
  }
#pragma unroll
  for (int off = 32; off > 0; off >>= 1) {
    d1 += __shfl_down(d1, off, 64);
    d2 += __shfl_down(d2, off, 64);
  }
  if (lane == 0) {
    s1[r] = d1;
    s2[r] = d2;
  }
}

// ---------------------------------------------------------------------------
// k_hiddenT: Ht[dout][row] = bf16(sum_din Wt[dout][din] * X[row][din])
// (row stride HTS). BM=BN=128, BK=32, 16x16x32 MFMA, depth-1 reg prefetch.
// ---------------------------------------------------------------------------
#define LDH 40

__global__ __launch_bounds__(256, 2) void k_hiddenT(const float* __restrict__ X,
                                                    const bf16* __restrict__ Wt,
                                                    bf16* __restrict__ Ht) {
  __shared__ bf16 As[128][LDH];
  __shared__ bf16 Bs[128][LDH];
  const int t = threadIdx.x;
  const int m0 = blockIdx.y * 128;
  const int n0 = blockIdx.x * 128;
  const int lane = t & 63, w = t >> 6;
  const int wm = w >> 1, wn = w & 1;
  const int l15 = lane & 15, q = lane >> 4;

  f32x4 acc[4][4];
#pragma unroll
  for (int i = 0; i < 4; ++i)
#pragma unroll
    for (int j = 0; j < 4; ++j) acc[i][j] = (f32x4){0.f, 0.f, 0.f, 0.f};

  bf16x8 av[2];
  float4 bv[4];
#pragma unroll
  for (int p = 0; p < 2; ++p) {
    int s = t + p * 256;
    av[p] = *(const bf16x8*)&Wt[(size_t)(m0 + (s >> 2)) * D_ + (s & 3) * 8];
  }
#pragma unroll
  for (int p = 0; p < 4; ++p) {
    int s = t + p * 256;
    bv[p] = *(const float4*)&X[(size_t)(n0 + (s >> 3)) * D_ + (s & 7) * 4];
  }

  for (int k0 = 0; k0 < D_; k0 += 32) {
    __syncthreads();
#pragma unroll
    for (int p = 0; p < 2; ++p) {
      int s = t + p * 256;
      *(bf16x8*)&As[s >> 2][(s & 3) * 8] = av[p];
    }
#pragma unroll
    for (int p = 0; p < 4; ++p) {
      int s = t + p * 256;
      float4 v = bv[p];
      bf16x4 h = {(bf16)v.x, (bf16)v.y, (bf16)v.z, (bf16)v.w};
      *(bf16x4*)&Bs[s >> 3][(s & 7) * 4] = h;
    }
    __syncthreads();
    if (k0 + 32 < D_) {
#pragma unroll
      for (int p = 0; p < 2; ++p) {
        int s = t + p * 256;
        av[p] = *(const bf16x8*)&Wt[(size_t)(m0 + (s >> 2)) * D_ + k0 + 32 + (s & 3) * 8];
      }
#pragma unroll
      for (int p = 0; p < 4; ++p) {
        int s = t + p * 256;
        bv[p] = *(const float4*)&X[(size_t)(n0 + (s >> 3)) * D_ + k0 + 32 + (s & 7) * 4];
      }
    }
    bf16x8 a[4], bb[4];
#pragma unroll
    for (int i = 0; i < 4; ++i)
      a[i] = *(const bf16x8*)&As[wm * 64 + i * 16 + l15][q * 8];
#pragma unroll
    for (int j = 0; j < 4; ++j)
      bb[j] = *(const bf16x8*)&Bs[wn * 64 + j * 16 + l15][q * 8];
#pragma unroll
    for (int i = 0; i < 4; ++i)
#pragma unroll
      for (int j = 0; j < 4; ++j)
        acc[i][j] =
            __builtin_amdgcn_mfma_f32_16x16x32_bf16(a[i], bb[j], acc[i][j], 0, 0, 0);
  }
#pragma unroll
  for (int i = 0; i < 4; ++i)
#pragma unroll
    for (int r = 0; r < 4; ++r) {
      int dout = m0 + wm * 64 + i * 16 + q * 4 + r;
#pragma unroll
      for (int j = 0; j < 4; ++j) {
        int row = n0 + wn * 64 + j * 16 + l15;
        Ht[(size_t)dout * HTS + row] = (bf16)acc[i][j][r];
      }
    }
}

// ---------------------------------------------------------------------------
// k_attn: out = elu( softmax_row(mask(leaky(s1_i+s2_j))) @ H )
// 64 rows x 512 d per block; 8 waves each own 64 d (2 n-tiles of 32).
// BK=128 chunks, 16 chunks, ONE barrier per chunk (Ps double-buffered).
// B-fragments (Ht) load directly global->VGPR (no LDS staging, no reuse
// existed anyway). Graph prefetched to regs one chunk ahead; exp for chunk
// p+1 computed in the shadow of chunk p's MFMAs.
// ---------------------------------------------------------------------------
#define AT_BM 64
#define AT_BK 128
#define NCHUNK (N_ / AT_BK)  // 16
#define LDPS 136             // Ps row stride (bf16): 272 B, 16B-aligned

__global__ __launch_bounds__(512, 1) void k_attn(const bf16* __restrict__ Ht,
                                                 const int* __restrict__ graph,
                                                 const float* __restrict__ s1,
                                                 const float* __restrict__ s2,
                                                 float* __restrict__ out) {
  __shared__ bf16 Ps[2][AT_BM][LDPS];   // 34.8 KB
  __shared__ float s2s[N_];             // 8 KB
  __shared__ float sum_part[AT_BM][8];  // 2 KB
  __shared__ float row_sum[AT_BM];

  const int t = threadIdx.x;
  const int b = blockIdx.y;
  const int i0 = blockIdx.x * AT_BM;
  const int lane = t & 63, w = t >> 6;
  const int r31 = lane & 31, half = lane >> 5;
  const int d0 = w * 64;

  const bf16* Htb = Ht + (size_t)b * N_;  // Htb[d*HTS + j]
  const int* Gb = graph + ((size_t)b * N_ + i0) * N_;

  for (int c = t; c < N_; c += 512) s2s[c] = s2[b * N_ + c];

  const int pi = t >> 3;        // P row 0..63
  const int pj = (t & 7) * 16;  // 16 j-values per thread
  const float s1r = s1[b * N_ + i0 + pi];
  float rsum = 0.f;

  f32x16 acc[2][2];
#pragma unroll
  for (int i = 0; i < 2; ++i)
#pragma unroll
    for (int j = 0; j < 2; ++j)
#pragma unroll
      for (int r = 0; r < 16; ++r) acc[i][j][r] = 0.f;

  // graph prefetch for chunk 0
  int gg[16];
#pragma unroll
  for (int u = 0; u < 4; ++u)
    *(int4*)&gg[u * 4] = *(const int4*)&Gb[(size_t)pi * N_ + pj + u * 4];

  __syncthreads();  // s2s ready

  float pv[16];
#pragma unroll
  for (int u = 0; u < 16; ++u) {
    float e = s1r + s2s[pj + u];
    e = (e > 0.f) ? e : NEG_ALPHA * e;
    float pe = (gg[u] != 0) ? __expf(e) : 0.f;
    pv[u] = pe;
    rsum += pe;
  }

  for (int p = 0; p < NCHUNK; ++p) {
    const int j0 = p * AT_BK;
    // publish P chunk p (buffer reuse guarded by barrier of iteration p-1)
    {
      bf16x8 w0 = {(bf16)pv[0], (bf16)pv[1], (bf16)pv[2], (bf16)pv[3],
                   (bf16)pv[4], (bf16)pv[5], (bf16)pv[6], (bf16)pv[7]};
      bf16x8 w1 = {(bf16)pv[8],  (bf16)pv[9],  (bf16)pv[10], (bf16)pv[11],
                   (bf16)pv[12], (bf16)pv[13], (bf16)pv[14], (bf16)pv[15]};
      *(bf16x8*)&Ps[p & 1][pi][pj] = w0;
      *(bf16x8*)&Ps[p & 1][pi][pj + 8] = w1;
    }
    // graph prefetch for chunk p+1 (register loads; in flight across barrier)
    if (p + 1 < NCHUNK) {
#pragma unroll
      for (int u = 0; u < 4; ++u)
        *(int4*)&gg[u * 4] =
            *(const int4*)&Gb[(size_t)pi * N_ + j0 + AT_BK + pj + u * 4];
    }
    __syncthreads();  // Ps[p&1] visible; prior readers of this buffer done
    // MFMA phase: B-frags straight from global (L2/L3), A-frags from LDS
#pragma unroll
    for (int ks = 0; ks < 8; ++ks) {
      const int ko = ks * 16 + half * 8;
      bf16x8 b0 = *(const bf16x8*)&Htb[(size_t)(d0 + r31) * HTS + j0 + ko];
      bf16x8 b1 = *(const bf16x8*)&Htb[(size_t)(d0 + 32 + r31) * HTS + j0 + ko];
      bf16x8 a0 = *(const bf16x8*)&Ps[p & 1][r31][ko];
      bf16x8 a1 = *(const bf16x8*)&Ps[p & 1][32 + r31][ko];
      acc[0][0] = __builtin_amdgcn_mfma_f32_32x32x16_bf16(a0, b0, acc[0][0], 0, 0, 0);
      acc[0][1] = __builtin_amdgcn_mfma_f32_32x32x16_bf16(a0, b1, acc[0][1], 0, 0, 0);
      acc[1][0] = __builtin_amdgcn_mfma_f32_32x32x16_bf16(a1, b0, acc[1][0], 0, 0, 0);
      acc[1][1] = __builtin_amdgcn_mfma_f32_32x32x16_bf16(a1, b1, acc[1][1], 0, 0, 0);
    }
    // compute pv for chunk p+1 in the MFMA shadow
    if (p + 1 < NCHUNK) {
#pragma unroll
      for (int u = 0; u < 16; ++u) {
        float e = s1r + s2s[j0 + AT_BK + pj + u];
        e = (e > 0.f) ? e : NEG_ALPHA * e;
        float pe = (gg[u] != 0) ? __expf(e) : 0.f;
        pv[u] = pe;
        rsum += pe;
      }
    }
  }

  // row sums
  sum_part[pi][t & 7] = rsum;
  __syncthreads();
  if (t < AT_BM) {
    float s = 0.f;
#pragma unroll
    for (int k = 0; k < 8; ++k) s += sum_part[t][k];
    row_sum[t] = s;
  }
  __syncthreads();

  // epilogue: normalize + elu + store
  // C/D (32x32): col = lane&31, row = (r&3) + 8*(r>>2) + 4*half
#pragma unroll
  for (int mt = 0; mt < 2; ++mt) {
    float inv[16];
#pragma unroll
    for (int r = 0; r < 16; ++r)
      inv[r] = 1.f / row_sum[mt * 32 + (r & 3) + 8 * (r >> 2) + 4 * half];
#pragma unroll
    for (int nt = 0; nt < 2; ++nt) {
      const int d = d0 + nt * 32 + r31;
#pragma unroll
      for (int r = 0; r < 16; ++r) {
        int i = mt * 32 + (r & 3) + 8 * (r >> 2) + 4 * half;
        float x = acc[mt][nt][r] * inv[r];
        out[((size_t)b * N_ + i0 + i) * D_ + d] = (x > 0.f) ? x : expm1f(x);
      }
    }
  }
}

// ---------------------------------------------------------------------------
extern "C" void kernel_launch(void* const* d_in, const int* in_sizes, int n_in,
                              void* d_out, int out_size, void* d_ws,
                              size_t ws_size, hipStream_t stream) {
  const float* X = (const float*)d_in[0];
  const int* graph = (const int*)d_in[1];
  const float* W = (const float*)d_in[2];
  const float* a1 = (const float*)d_in[3];
  const float* a2 = (const float*)d_in[4];
  float* out = (float*)d_out;

  char* ws = (char*)d_ws;
  bf16* Wt = (bf16*)ws;                     // 512 KB
  bf16* Ht = (bf16*)(ws + (1 << 19));       // 512*HTS*2 = ~16.03 MB
  float* s1 = (float*)(ws + (1 << 19) + (size_t)D_ * HTS * 2);
  float* s2 = s1 + NROWS;
  float* wa1 = s2 + NROWS;
  float* wa2 = wa1 + D_;

  hipLaunchKernelGGL(k_prep_wa, dim3(512), dim3(256), 0, stream, W, a1, a2, Wt,
                     wa1, wa2);
  hipLaunchKernelGGL(k_scores_x, dim3(NROWS / 4), dim3(256), 0, stream, X, wa1,
                     wa2, s1, s2);
  hipLaunchKernelGGL(k_hiddenT, dim3(NROWS / 128, D_ / 128), dim3(256), 0,
                     stream, X, Wt, Ht);
  hipLaunchKernelGGL(k_attn, dim3(N_ / AT_BM, B_), dim3(512), 0, stream, Ht,
                     graph, s1, s2, out);
}